// Round 4
// baseline (107.189 us; speedup 1.0000x reference)
//
#include <hip/hip_runtime.h>
#include <hip/hip_cooperative_groups.h>
#include <math.h>

namespace cg = cooperative_groups;

// Problem constants (fixed by the reference)
constexpr int B_ROWS = 16384;
constexpr int D_COLS = 2048;     // 512 float4 per row
constexpr float EPS_F = 1e-8f;
constexpr int P = 256;           // blocks; 1 per CU, co-resident for coop launch
constexpr int RPB = B_ROWS / P;  // 64 contiguous rows per block

// ws float layout (every location plain-stored before read; no memset):
//  [0 .. 1024)            per-block counts, float4 per block {c0,c1,c2,c3}
//  [2048 .. 2048+3072)    per-block dot partials, 12 floats x 256 blocks
//  [16384 .. +P*8192)     per-block partials: block p, float4 index g*512+c
constexpr int WS_DOTS = 2048;
constexpr int WS_PART = 16384;   // byte offset 65536, 16B aligned

// ---------------------------------------------------------------------------
// One cooperative kernel, three phases separated by grid.sync():
//  A: block b sums rows [64b,64b+64) via one-hot-weight FMA (branchless)
//  B: block b reduces float4 columns [8b,8b+8) of all 4 groups across the
//     256 partials, computes its partial contribution to the 10 dot products
//  C: block 0 reduces 256 dot records + 256 count records -> 4 outputs
//     center_loss = 1 - (sum_g ||S_g||)/B   (inputs are unit-norm)
// ---------------------------------------------------------------------------
__global__ __launch_bounds__(512) void fused_loss(
    const float* __restrict__ feat, const int* __restrict__ lab,
    const int* __restrict__ ses, float* __restrict__ ws,
    float* __restrict__ out) {
  cg::grid_group grid = cg::this_grid();
  const int t = threadIdx.x;
  const int b = blockIdx.x;

  // ---------------- Phase A ----------------
  __shared__ float4 w[RPB];
  if (t < RPB) {
    const int r = b * RPB + t;
    const int g = lab[r] * 2 + ses[r];
    w[t] = make_float4(g == 0 ? 1.f : 0.f, g == 1 ? 1.f : 0.f,
                       g == 2 ? 1.f : 0.f, g == 3 ? 1.f : 0.f);
  }
  __syncthreads();

  {
    float4 a0 = {0.f, 0.f, 0.f, 0.f};
    float4 a1 = a0, a2 = a0, a3 = a0;
    const float4* fb = (const float4*)feat + (size_t)b * RPB * 512 + t;
    #pragma unroll 8
    for (int r = 0; r < RPB; ++r) {
      const float4 v = fb[(size_t)r * 512];
      const float4 wr = w[r];
      a0.x += v.x * wr.x; a0.y += v.y * wr.x; a0.z += v.z * wr.x; a0.w += v.w * wr.x;
      a1.x += v.x * wr.y; a1.y += v.y * wr.y; a1.z += v.z * wr.y; a1.w += v.w * wr.y;
      a2.x += v.x * wr.z; a2.y += v.y * wr.z; a2.z += v.z * wr.z; a2.w += v.w * wr.z;
      a3.x += v.x * wr.w; a3.y += v.y * wr.w; a3.z += v.z * wr.w; a3.w += v.w * wr.w;
    }
    float4* part = (float4*)(ws + WS_PART) + (size_t)b * 2048;
    part[t]        = a0;
    part[512 + t]  = a1;
    part[1024 + t] = a2;
    part[1536 + t] = a3;
    if (t == 0) {
      float4 c = {0.f, 0.f, 0.f, 0.f};
      #pragma unroll
      for (int r = 0; r < RPB; ++r) {
        const float4 wr = w[r];
        c.x += wr.x; c.y += wr.y; c.z += wr.z; c.w += wr.w;
      }
      ((float4*)ws)[b] = c;
    }
  }

  grid.sync();

  // ---------------- Phase B ----------------
  // 32 (g,cl) pairs per block: pair = t&31 (g=pair>>3, cl=pair&7), chunk=t>>5.
  {
    const int pair = t & 31;
    const int chunk = t >> 5;              // 0..15
    const int g = pair >> 3;
    const int cl = pair & 7;
    const int j4 = g * 512 + b * 8 + cl;

    float4 s = {0.f, 0.f, 0.f, 0.f};
    const float4* part = (const float4*)(ws + WS_PART);
    for (int p = chunk; p < P; p += 16) {
      const float4 v = part[(size_t)p * 2048 + j4];
      s.x += v.x; s.y += v.y; s.z += v.z; s.w += v.w;
    }

    __shared__ float4 lds[512];
    lds[t] = s;
    __syncthreads();

    __shared__ float4 sg[4][8];            // [g][cl] = S_g for this column
    if (t < 32) {
      float4 acc = lds[t];
      #pragma unroll
      for (int ch = 1; ch < 16; ++ch) {
        const float4 v = lds[ch * 32 + t];
        acc.x += v.x; acc.y += v.y; acc.z += v.z; acc.w += v.w;
      }
      sg[t >> 3][t & 7] = acc;
    }
    __syncthreads();

    if (t == 0) {
      float n0 = 0, n1 = 0, n2 = 0, n3 = 0;
      float d01 = 0, d23 = 0, d02 = 0, d03 = 0, d12 = 0, d13 = 0;
      #pragma unroll
      for (int cl2 = 0; cl2 < 8; ++cl2) {
        const float4 s0 = sg[0][cl2], s1 = sg[1][cl2];
        const float4 s2 = sg[2][cl2], s3 = sg[3][cl2];
        n0 += s0.x*s0.x + s0.y*s0.y + s0.z*s0.z + s0.w*s0.w;
        n1 += s1.x*s1.x + s1.y*s1.y + s1.z*s1.z + s1.w*s1.w;
        n2 += s2.x*s2.x + s2.y*s2.y + s2.z*s2.z + s2.w*s2.w;
        n3 += s3.x*s3.x + s3.y*s3.y + s3.z*s3.z + s3.w*s3.w;
        d01 += s0.x*s1.x + s0.y*s1.y + s0.z*s1.z + s0.w*s1.w;
        d23 += s2.x*s3.x + s2.y*s3.y + s2.z*s3.z + s2.w*s3.w;
        d02 += s0.x*s2.x + s0.y*s2.y + s0.z*s2.z + s0.w*s2.w;
        d03 += s0.x*s3.x + s0.y*s3.y + s0.z*s3.z + s0.w*s3.w;
        d12 += s1.x*s2.x + s1.y*s2.y + s1.z*s2.z + s1.w*s2.w;
        d13 += s1.x*s3.x + s1.y*s3.y + s1.z*s3.z + s1.w*s3.w;
      }
      float* dst = ws + WS_DOTS + b * 12;
      dst[0] = n0;  dst[1] = n1;  dst[2] = n2;  dst[3] = n3;
      dst[4] = d01; dst[5] = d23; dst[6] = d02; dst[7] = d03;
      dst[8] = d12; dst[9] = d13; dst[10] = 0.f; dst[11] = 0.f;
    }
  }

  grid.sync();

  // ---------------- Phase C (block 0 only) ----------------
  if (b == 0) {
    float n0 = 0, n1 = 0, n2 = 0, n3 = 0;
    float d01 = 0, d23 = 0, d02 = 0, d03 = 0, d12 = 0, d13 = 0;
    float k0 = 0, k1 = 0, k2 = 0, k3 = 0;

    if (t < 256) {
      const float* src = ws + WS_DOTS + t * 12;
      n0 = src[0]; n1 = src[1]; n2 = src[2]; n3 = src[3];
      d01 = src[4]; d23 = src[5]; d02 = src[6]; d03 = src[7];
      d12 = src[8]; d13 = src[9];
      const float4 c = ((const float4*)ws)[t];
      k0 = c.x; k1 = c.y; k2 = c.z; k3 = c.w;
    }

    #pragma unroll
    for (int m = 32; m >= 1; m >>= 1) {
      n0  += __shfl_xor(n0, m, 64);  n1  += __shfl_xor(n1, m, 64);
      n2  += __shfl_xor(n2, m, 64);  n3  += __shfl_xor(n3, m, 64);
      d01 += __shfl_xor(d01, m, 64); d23 += __shfl_xor(d23, m, 64);
      d02 += __shfl_xor(d02, m, 64); d03 += __shfl_xor(d03, m, 64);
      d12 += __shfl_xor(d12, m, 64); d13 += __shfl_xor(d13, m, 64);
      k0  += __shfl_xor(k0, m, 64);  k1  += __shfl_xor(k1, m, 64);
      k2  += __shfl_xor(k2, m, 64);  k3  += __shfl_xor(k3, m, 64);
    }

    __shared__ float red[8][14];
    const int wv = t >> 6, ln = t & 63;
    if (ln == 0) {
      red[wv][0] = n0;  red[wv][1] = n1;  red[wv][2] = n2;  red[wv][3] = n3;
      red[wv][4] = d01; red[wv][5] = d23; red[wv][6] = d02; red[wv][7] = d03;
      red[wv][8] = d12; red[wv][9] = d13;
      red[wv][10] = k0; red[wv][11] = k1; red[wv][12] = k2; red[wv][13] = k3;
    }
    __syncthreads();

    if (t == 0) {
      float v[14];
      #pragma unroll
      for (int k = 0; k < 14; ++k) {
        v[k] = 0.f;
        #pragma unroll
        for (int wv2 = 0; wv2 < 8; ++wv2) v[k] += red[wv2][k];
      }

      const float NS0 = sqrtf(v[0]), NS1 = sqrtf(v[1]);
      const float NS2 = sqrtf(v[2]), NS3 = sqrtf(v[3]);
      const float cn0 = v[10], cn1 = v[11], cn2 = v[12], cn3 = v[13];
      const float N0 = NS0 / cn0, N1 = NS1 / cn1;
      const float N2 = NS2 / cn2, N3 = NS3 / cn3;

      const float c01 = (v[4] / (cn0 * cn1)) / fmaxf(N0 * N1, EPS_F);
      const float c23 = (v[5] / (cn2 * cn3)) / fmaxf(N2 * N3, EPS_F);
      const float c02 = (v[6] / (cn0 * cn2)) / fmaxf(N0 * N2, EPS_F);
      const float c03 = (v[7] / (cn0 * cn3)) / fmaxf(N0 * N3, EPS_F);
      const float c12 = (v[8] / (cn1 * cn2)) / fmaxf(N1 * N2, EPS_F);
      const float c13 = (v[9] / (cn1 * cn3)) / fmaxf(N1 * N3, EPS_F);

      const float center_loss = 1.0f - (NS0 + NS1 + NS2 + NS3) * (1.0f / (float)B_ROWS);
      const float align_loss = ((1.0f - c01) + (1.0f - c23)) * 0.5f;
      const float margin_loss = (c02 + c03 + c12 + c13) * 0.25f;

      out[0] = center_loss + 0.1f * align_loss + 0.05f * margin_loss;
      out[1] = center_loss;
      out[2] = align_loss;
      out[3] = margin_loss;
    }
  }
}

extern "C" void kernel_launch(void* const* d_in, const int* in_sizes, int n_in,
                              void* d_out, int out_size, void* d_ws, size_t ws_size,
                              hipStream_t stream) {
  const float* feat = (const float*)d_in[0];
  const int* lab = (const int*)d_in[1];
  const int* ses = (const int*)d_in[2];
  float* ws = (float*)d_ws;
  float* out = (float*)d_out;

  void* args[] = {(void*)&feat, (void*)&lab, (void*)&ses, (void*)&ws, (void*)&out};
  hipLaunchCooperativeKernel(reinterpret_cast<void*>(fused_loss),
                             dim3(P), dim3(512), args, 0, stream);
}

// Round 5
// 36.443 us; speedup vs baseline: 2.9413x; 2.9413x over previous
//
#include <hip/hip_runtime.h>
#include <math.h>

// Problem constants (fixed by the reference)
constexpr int B_ROWS = 16384;
constexpr int D_COLS = 2048;     // 512 float4 per row
constexpr float EPS_F = 1e-8f;

// pass1 tiling: block = (row-chunk rb of 64 rows) x (col-slice cs of 64 float4)
constexpr int NRB = 256;         // row chunks (64 rows each)
constexpr int NCS = 8;           // col slices (64 float4 each)
constexpr int ROWS_PER_RB = 64;
constexpr int ROWS_PER_H = 16;   // 4 row-subsets per column-thread

// ws float layout (every location plain-stored before read; no memset):
//  [0 .. 1024)             per-rb counts, float4 {c0,c1,c2,c3} x 256
//  [2048 .. 2048+1536)     per-pass2-block dot partials, 12 floats x 128
//  [16384 .. +256*8192)    partials: record rb (8192 floats = 4 groups x 2048)
constexpr int WS_DOTS = 2048;
constexpr int WS_PART = 16384;   // byte offset 65536, 16B aligned

// ---------------------------------------------------------------------------
// pass1: 2048 blocks x 256 threads, 8 blocks/CU (32 waves/CU).
// Thread (c = t&63, h = t>>6) accumulates 16 rows of float4 column
// cs*64+c into 4 one-hot-weighted group accumulators; LDS-combines the 4
// row-subsets; 256 threads store the 4x64 float4 slice of record rb.
// ---------------------------------------------------------------------------
__global__ __launch_bounds__(256, 8) void pass1_partial_sums(
    const float* __restrict__ feat, const int* __restrict__ lab,
    const int* __restrict__ ses, float* __restrict__ ws) {
  const int t = threadIdx.x;
  const int rb = blockIdx.x >> 3;
  const int cs = blockIdx.x & 7;
  const int c = t & 63;
  const int h = t >> 6;
  const int row0 = rb * ROWS_PER_RB;

  __shared__ float4 w[ROWS_PER_RB];
  __shared__ float4 red[16 * 64];   // [(g*4+h)*64 + c], 16 KB

  if (t < ROWS_PER_RB) {
    const int r = row0 + t;
    const int g = lab[r] * 2 + ses[r];
    w[t] = make_float4(g == 0 ? 1.f : 0.f, g == 1 ? 1.f : 0.f,
                       g == 2 ? 1.f : 0.f, g == 3 ? 1.f : 0.f);
  }
  __syncthreads();

  float4 a0 = {0.f, 0.f, 0.f, 0.f};
  float4 a1 = a0, a2 = a0, a3 = a0;

  const float4* fb = (const float4*)feat
      + (size_t)(row0 + h * ROWS_PER_H) * 512 + cs * 64 + c;
  #pragma unroll 4
  for (int r = 0; r < ROWS_PER_H; ++r) {
    const float4 v = fb[(size_t)r * 512];
    const float4 wr = w[h * ROWS_PER_H + r];
    a0.x += v.x * wr.x; a0.y += v.y * wr.x; a0.z += v.z * wr.x; a0.w += v.w * wr.x;
    a1.x += v.x * wr.y; a1.y += v.y * wr.y; a1.z += v.z * wr.y; a1.w += v.w * wr.y;
    a2.x += v.x * wr.z; a2.y += v.y * wr.z; a2.z += v.z * wr.z; a2.w += v.w * wr.z;
    a3.x += v.x * wr.w; a3.y += v.y * wr.w; a3.z += v.z * wr.w; a3.w += v.w * wr.w;
  }

  red[(0 * 4 + h) * 64 + c] = a0;
  red[(1 * 4 + h) * 64 + c] = a1;
  red[(2 * 4 + h) * 64 + c] = a2;
  red[(3 * 4 + h) * 64 + c] = a3;
  __syncthreads();

  // thread t: group g = t>>6, column c = t&63; sum the 4 row-subsets
  {
    const int g = t >> 6;
    float4 acc = red[(g * 4 + 0) * 64 + c];
    #pragma unroll
    for (int hh = 1; hh < 4; ++hh) {
      const float4 v = red[(g * 4 + hh) * 64 + c];
      acc.x += v.x; acc.y += v.y; acc.z += v.z; acc.w += v.w;
    }
    float4* part = (float4*)(ws + WS_PART);
    part[(size_t)rb * 2048 + g * 512 + cs * 64 + c] = acc;
  }

  if (cs == 0 && t == 0) {
    float4 cnt = {0.f, 0.f, 0.f, 0.f};
    #pragma unroll
    for (int r = 0; r < ROWS_PER_RB; ++r) {
      const float4 wr = w[r];
      cnt.x += wr.x; cnt.y += wr.y; cnt.z += wr.z; cnt.w += wr.w;
    }
    ((float4*)ws)[rb] = cnt;
  }
}

// ---------------------------------------------------------------------------
// pass2: reduce 256 records -> per-block dot partials. 128 blocks x 256 thr.
// Block owns 4 float4 columns across all 4 groups (16 j4 values); thread:
// pair = t&15 (g=pair>>2, cl=pair&3), chunk = t>>4 (16 records each).
// ---------------------------------------------------------------------------
__global__ __launch_bounds__(256) void pass2_reduce(float* __restrict__ ws) {
  const int t = threadIdx.x;
  const int pair = t & 15;
  const int chunk = t >> 4;            // 0..15
  const int g = pair >> 2;
  const int cl = pair & 3;
  const int j4 = g * 512 + blockIdx.x * 4 + cl;

  float4 s = {0.f, 0.f, 0.f, 0.f};
  const float4* part = (const float4*)(ws + WS_PART);
  for (int p = chunk; p < NRB; p += 16) {
    const float4 v = part[(size_t)p * 2048 + j4];
    s.x += v.x; s.y += v.y; s.z += v.z; s.w += v.w;
  }

  __shared__ float4 lds[256];
  lds[t] = s;
  __syncthreads();

  __shared__ float4 sg[4][4];          // [g][cl] = S_g for this float4 column
  if (t < 16) {
    float4 acc = lds[t];
    #pragma unroll
    for (int ch = 1; ch < 16; ++ch) {
      const float4 v = lds[ch * 16 + t];
      acc.x += v.x; acc.y += v.y; acc.z += v.z; acc.w += v.w;
    }
    sg[t >> 2][t & 3] = acc;
  }
  __syncthreads();

  if (t == 0) {
    float n0 = 0, n1 = 0, n2 = 0, n3 = 0;
    float d01 = 0, d23 = 0, d02 = 0, d03 = 0, d12 = 0, d13 = 0;
    #pragma unroll
    for (int cl2 = 0; cl2 < 4; ++cl2) {
      const float4 s0 = sg[0][cl2], s1 = sg[1][cl2];
      const float4 s2 = sg[2][cl2], s3 = sg[3][cl2];
      n0 += s0.x*s0.x + s0.y*s0.y + s0.z*s0.z + s0.w*s0.w;
      n1 += s1.x*s1.x + s1.y*s1.y + s1.z*s1.z + s1.w*s1.w;
      n2 += s2.x*s2.x + s2.y*s2.y + s2.z*s2.z + s2.w*s2.w;
      n3 += s3.x*s3.x + s3.y*s3.y + s3.z*s3.z + s3.w*s3.w;
      d01 += s0.x*s1.x + s0.y*s1.y + s0.z*s1.z + s0.w*s1.w;
      d23 += s2.x*s3.x + s2.y*s3.y + s2.z*s3.z + s2.w*s3.w;
      d02 += s0.x*s2.x + s0.y*s2.y + s0.z*s2.z + s0.w*s2.w;
      d03 += s0.x*s3.x + s0.y*s3.y + s0.z*s3.z + s0.w*s3.w;
      d12 += s1.x*s2.x + s1.y*s2.y + s1.z*s2.z + s1.w*s2.w;
      d13 += s1.x*s3.x + s1.y*s3.y + s1.z*s3.z + s1.w*s3.w;
    }
    float* dst = ws + WS_DOTS + blockIdx.x * 12;
    dst[0] = n0;  dst[1] = n1;  dst[2] = n2;  dst[3] = n3;
    dst[4] = d01; dst[5] = d23; dst[6] = d02; dst[7] = d03;
    dst[8] = d12; dst[9] = d13; dst[10] = 0.f; dst[11] = 0.f;
  }
}

// ---------------------------------------------------------------------------
// pass3: sum 128 dot records + 256 count records -> 4 outputs.
//   center_loss = 1 - (sum_g ||S_g||)/B   (inputs are unit-norm)
// ---------------------------------------------------------------------------
__global__ __launch_bounds__(256) void pass3_finalize(
    const float* __restrict__ ws, float* __restrict__ out) {
  const int t = threadIdx.x;
  float n0 = 0, n1 = 0, n2 = 0, n3 = 0;
  float d01 = 0, d23 = 0, d02 = 0, d03 = 0, d12 = 0, d13 = 0;
  float k0 = 0, k1 = 0, k2 = 0, k3 = 0;

  if (t < 128) {
    const float* src = ws + WS_DOTS + t * 12;
    n0 = src[0]; n1 = src[1]; n2 = src[2]; n3 = src[3];
    d01 = src[4]; d23 = src[5]; d02 = src[6]; d03 = src[7];
    d12 = src[8]; d13 = src[9];
  }
  {
    const float4 cta = ((const float4*)ws)[t];             // 256 count records
    k0 = cta.x; k1 = cta.y; k2 = cta.z; k3 = cta.w;
  }

  #pragma unroll
  for (int m = 32; m >= 1; m >>= 1) {
    n0  += __shfl_xor(n0, m, 64);  n1  += __shfl_xor(n1, m, 64);
    n2  += __shfl_xor(n2, m, 64);  n3  += __shfl_xor(n3, m, 64);
    d01 += __shfl_xor(d01, m, 64); d23 += __shfl_xor(d23, m, 64);
    d02 += __shfl_xor(d02, m, 64); d03 += __shfl_xor(d03, m, 64);
    d12 += __shfl_xor(d12, m, 64); d13 += __shfl_xor(d13, m, 64);
    k0  += __shfl_xor(k0, m, 64);  k1  += __shfl_xor(k1, m, 64);
    k2  += __shfl_xor(k2, m, 64);  k3  += __shfl_xor(k3, m, 64);
  }

  __shared__ float red[4][14];
  const int wv = t >> 6, ln = t & 63;
  if (ln == 0) {
    red[wv][0] = n0;  red[wv][1] = n1;  red[wv][2] = n2;  red[wv][3] = n3;
    red[wv][4] = d01; red[wv][5] = d23; red[wv][6] = d02; red[wv][7] = d03;
    red[wv][8] = d12; red[wv][9] = d13;
    red[wv][10] = k0; red[wv][11] = k1; red[wv][12] = k2; red[wv][13] = k3;
  }
  __syncthreads();

  if (t == 0) {
    float v[14];
    #pragma unroll
    for (int k = 0; k < 14; ++k)
      v[k] = red[0][k] + red[1][k] + red[2][k] + red[3][k];

    const float NS0 = sqrtf(v[0]), NS1 = sqrtf(v[1]);
    const float NS2 = sqrtf(v[2]), NS3 = sqrtf(v[3]);
    const float cn0 = v[10], cn1 = v[11], cn2 = v[12], cn3 = v[13];
    const float N0 = NS0 / cn0, N1 = NS1 / cn1;
    const float N2 = NS2 / cn2, N3 = NS3 / cn3;

    const float c01 = (v[4] / (cn0 * cn1)) / fmaxf(N0 * N1, EPS_F);
    const float c23 = (v[5] / (cn2 * cn3)) / fmaxf(N2 * N3, EPS_F);
    const float c02 = (v[6] / (cn0 * cn2)) / fmaxf(N0 * N2, EPS_F);
    const float c03 = (v[7] / (cn0 * cn3)) / fmaxf(N0 * N3, EPS_F);
    const float c12 = (v[8] / (cn1 * cn2)) / fmaxf(N1 * N2, EPS_F);
    const float c13 = (v[9] / (cn1 * cn3)) / fmaxf(N1 * N3, EPS_F);

    const float center_loss = 1.0f - (NS0 + NS1 + NS2 + NS3) * (1.0f / (float)B_ROWS);
    const float align_loss = ((1.0f - c01) + (1.0f - c23)) * 0.5f;
    const float margin_loss = (c02 + c03 + c12 + c13) * 0.25f;

    out[0] = center_loss + 0.1f * align_loss + 0.05f * margin_loss;
    out[1] = center_loss;
    out[2] = align_loss;
    out[3] = margin_loss;
  }
}

extern "C" void kernel_launch(void* const* d_in, const int* in_sizes, int n_in,
                              void* d_out, int out_size, void* d_ws, size_t ws_size,
                              hipStream_t stream) {
  const float* feat = (const float*)d_in[0];
  const int* lab = (const int*)d_in[1];
  const int* ses = (const int*)d_in[2];
  float* ws = (float*)d_ws;
  float* out = (float*)d_out;

  hipLaunchKernelGGL(pass1_partial_sums, dim3(NRB * NCS), dim3(256), 0, stream,
                     feat, lab, ses, ws);
  hipLaunchKernelGGL(pass2_reduce, dim3(128), dim3(256), 0, stream, ws);
  hipLaunchKernelGGL(pass3_finalize, dim3(1), dim3(256), 0, stream, ws, out);
}